// Round 2
// 128.667 us; speedup vs baseline: 1.0399x; 1.0399x over previous
//
#include <hip/hip_runtime.h>

// Problem constants (from reference: shape (32,1,512,512) fp32)
#define BATCH 32
#define H 512
#define W 512
#define N_TOT (BATCH * H * W)   // 8388608
#define BAND 8                  // output rows per wave
#define NBLOCKS 1024

// Streaming row-band kernel with rolling register reuse.
// Wave = 64 lanes x 4 px = half a 512-px row. Each wave owns BAND=8
// consecutive output rows of one image half and walks them with a 4-slot
// register ring (slot = row & 3; r0 is a multiple of 8, so every slot index
// is a compile-time constant after unrolling -> SROA keeps it in registers).
// Per iteration: issue the NEXT row's loads (3 float4 + 6 halo dwords, halo
// is an L1 hit), then compute the CURRENT output row from data loaded a full
// iteration ago -> per-wave load/compute overlap, plus 4 waves/SIMD (all
// 4096 waves co-resident) for cross-wave hiding.
//
// R1: single-address cross-XCD atomicAdd finish (1024 fp32 atomics to one
// dword) serializes at the device coherent point -> ~25 us empty-machine
// drain tail (OccupancyPercent 17% avg vs ~50% resident). Replaced with
// per-block plain stores to distinct d_ws slots (parallel drain) + 1-block
// finish kernel. Defensive fallback to the old atomic path if ws_size is
// ever too small (guards against a GPU fault killing the container).

template <bool USE_PARTIALS>
__global__ __launch_bounds__(256)
void fusion_loss_kernel(const float* __restrict__ A,
                        const float* __restrict__ B,
                        const float* __restrict__ F,
                        const int* __restrict__ scheme_arr,
                        float* __restrict__ sink)   // partials[] or out scalar
{
    __shared__ float red[4];

    const int t    = threadIdx.x;
    const int lane = t & 63;
    const int ty   = t >> 6;
    const int wave = blockIdx.x * 4 + ty;      // 4096 waves total
    const int half = wave & 1;                 // left/right 256-px half
    const int band = wave >> 1;                // 2048 bands
    const int b    = band >> 6;                // batch (64 bands per image)
    const int r0   = (band & 63) << 3;         // first output row (mult of 8)
    const int x0   = (half << 8) + (lane << 2);
    const int base = b * (H * W);
    const int scheme = scheme_arr[b];
    const bool has_l = (x0 > 0);
    const bool has_r = (x0 + 4 < W);

    const float* __restrict__ imgs[3] = {A, B, F};

    // rolling ring: rc = center 4 px, rl/rh = 1-px halo each side
    float4 rc[3][4];
    float  rl[3][4];
    float  rh[3][4];

    auto load_row = [&](int y, int slot) {
        const bool rv = (unsigned)y < (unsigned)H;   // wave-uniform
#pragma unroll
        for (int im = 0; im < 3; ++im) {
            float4 c = make_float4(0.f, 0.f, 0.f, 0.f);
            float lf = 0.f, rt = 0.f;
            if (rv) {
                const float* row = imgs[im] + base + y * W;
                c  = *reinterpret_cast<const float4*>(row + x0);
                lf = has_l ? row[x0 - 1] : 0.f;   // L1 hit (neighbor's line)
                rt = has_r ? row[x0 + 4] : 0.f;   // L1 hit
            }
            rc[im][slot] = c;
            rl[im][slot] = lf;
            rh[im][slot] = rt;
        }
    };

    // preload rows r0-1, r0, r0+1 (slots 3, 0, 1; OOB rows load as zeros,
    // which is exactly the reference's zero padding)
    load_row(r0 - 1, 3);
    load_row(r0,     0);
    load_row(r0 + 1, 1);

    float acc = 0.f;

#pragma unroll
    for (int k = 0; k < BAND; ++k) {
        // prefetch row r0+k+2 into the slot holding dead row r0+k-2
        if (k < BAND - 1) load_row(r0 + k + 2, (k + 2) & 3);

        const int sm = (k + 3) & 3;   // row r0+k-1
        const int sc = k & 3;         // row r0+k
        const int sp = (k + 1) & 3;   // row r0+k+1

        float sobM[4];
#pragma unroll
        for (int im = 0; im < 3; ++im) {
            float gx[4], gy[4];
            {   // top row: gx = h1m, gy = h2m
                const float4 c4 = rc[im][sm];
                const float v[6] = {rl[im][sm], c4.x, c4.y, c4.z, c4.w, rh[im][sm]};
#pragma unroll
                for (int j = 0; j < 4; ++j) {
                    gx[j] = v[j + 2] - v[j];
                    gy[j] = v[j] + 2.f * v[j + 1] + v[j + 2];
                }
            }
            {   // center row: gx += 2*h1c
                const float4 c4 = rc[im][sc];
                const float v[6] = {rl[im][sc], c4.x, c4.y, c4.z, c4.w, rh[im][sc]};
#pragma unroll
                for (int j = 0; j < 4; ++j)
                    gx[j] += 2.f * (v[j + 2] - v[j]);
            }
            {   // bottom row: gx += h1p, gy -= h2p
                const float4 c4 = rc[im][sp];
                const float v[6] = {rl[im][sp], c4.x, c4.y, c4.z, c4.w, rh[im][sp]};
#pragma unroll
                for (int j = 0; j < 4; ++j) {
                    gx[j] += v[j + 2] - v[j];
                    gy[j] -= v[j] + 2.f * v[j + 1] + v[j + 2];
                }
            }
#pragma unroll
            for (int j = 0; j < 4; ++j) {
                const float sob = fabsf(gx[j]) + fabsf(gy[j]);
                if (im == 0)      sobM[j] = sob;
                else if (im == 1) sobM[j] = fmaxf(sobM[j], sob);
                else              acc += fabsf(sob - sobM[j]);
            }
        }

        // l_loss on the center row's 4 px (each pixel counted exactly once)
        {
            const float4 a4 = rc[0][sc], b4 = rc[1][sc], f4 = rc[2][sc];
            const float av[4] = {a4.x, a4.y, a4.z, a4.w};
            const float bv[4] = {b4.x, b4.y, b4.z, b4.w};
            const float fv[4] = {f4.x, f4.y, f4.z, f4.w};
#pragma unroll
            for (int j = 0; j < 4; ++j) {
                const float ab = (scheme == 0) ? 0.5f * (av[j] + bv[j])
                               : (scheme == 1) ? fmaxf(av[j], bv[j])
                               : 0.f;
                acc += fabsf(ab - fv[j]);
            }
        }
    }

    // ---- reduction: 64-lane shuffle, cross-wave via LDS ----
#pragma unroll
    for (int off = 32; off > 0; off >>= 1)
        acc += __shfl_down(acc, off, 64);
    if (lane == 0) red[ty] = acc;
    __syncthreads();
    if (t == 0) {
        const float s = red[0] + red[1] + red[2] + red[3];
        if (USE_PARTIALS)
            sink[blockIdx.x] = s;                       // parallel drain
        else
            atomicAdd(sink, s * (1.0f / (float)N_TOT)); // fallback path
    }
}

// 1-block finish: sum NBLOCKS partials (256 threads x 1 float4 = 1024
// floats), scale by 1/N, write the scalar. Kernel boundary on the stream
// guarantees visibility of kernel1's plain stores.
__global__ __launch_bounds__(256)
void fusion_finish(const float* __restrict__ partials, float* __restrict__ out)
{
    __shared__ float red[4];
    const int t    = threadIdx.x;
    const int lane = t & 63;
    const int ty   = t >> 6;

    const float4 p = reinterpret_cast<const float4*>(partials)[t];
    float v = (p.x + p.y) + (p.z + p.w);
#pragma unroll
    for (int off = 32; off > 0; off >>= 1)
        v += __shfl_down(v, off, 64);
    if (lane == 0) red[ty] = v;
    __syncthreads();
    if (t == 0)
        out[0] = (red[0] + red[1] + red[2] + red[3]) * (1.0f / (float)N_TOT);
}

extern "C" void kernel_launch(void* const* d_in, const int* in_sizes, int n_in,
                              void* d_out, int out_size, void* d_ws, size_t ws_size,
                              hipStream_t stream)
{
    const float* A = (const float*)d_in[0];
    const float* B = (const float*)d_in[1];
    const float* F = (const float*)d_in[2];
    const int* scheme = (const int*)d_in[3];
    float* out = (float*)d_out;

    if (d_ws != nullptr && ws_size >= NBLOCKS * sizeof(float)) {
        float* partials = (float*)d_ws;   // 4 KB, 16B-aligned
        fusion_loss_kernel<true><<<dim3(NBLOCKS), dim3(256), 0, stream>>>(
            A, B, F, scheme, partials);
        fusion_finish<<<dim3(1), dim3(256), 0, stream>>>(partials, out);
    } else {
        // Fallback: previous verified atomic path (d_out poisoned -> zero it).
        hipMemsetAsync(out, 0, sizeof(float), stream);
        fusion_loss_kernel<false><<<dim3(NBLOCKS), dim3(256), 0, stream>>>(
            A, B, F, scheme, out);
    }
}